// Round 7
// baseline (1527.812 us; speedup 1.0000x reference)
//
#include <hip/hip_runtime.h>
#include <cmath>

#define B_ 128
#define T_ 1024
#define D_ 128
#define U_ 256
#define EPS_ 0.01f
#define GAMMA_ 0.01f
#define NB 16            // batches per scan block
#define NBLK (B_ / NB)   // 8 scan blocks

typedef __attribute__((ext_vector_type(8))) short bf16x8;
typedef __attribute__((ext_vector_type(4))) float f32x4;

// f32 -> bf16 round-to-nearest-even
static __device__ __forceinline__ short f2bf(float f) {
  unsigned u = __builtin_bit_cast(unsigned, f);
  unsigned r = (u + 0x7FFFu + ((u >> 16) & 1u)) >> 16;
  return (short)r;
}

// Swizzled byte offset into one bf16 state buffer s[16 rows][256 units].
// Row stride 512 B; XOR bits 4-6 with (row&7) -> b128 fragment reads are
// conflict-free (verified: lanes sharing a bank pattern are 2-way = free).
static __device__ __forceinline__ int sb_byte(int j, int u) {
  return j * 512 + ((u * 2) ^ ((j & 7) << 4));
}

// ================= Kernel 1: h = x @ V + bias (f32, unchanged) =============
#define HG_ROWS 32

__global__ __launch_bounds__(256) void h_gemm_kernel(
    const float* __restrict__ x, const float* __restrict__ V,
    const float* __restrict__ bias, float* __restrict__ out)
{
  const int tid = threadIdx.x;
  const size_t row0 = (size_t)blockIdx.x * HG_ROWS;

  __shared__ float xs[HG_ROWS][D_];
  __shared__ float vs[32][U_];

  {
    const float4* xg = reinterpret_cast<const float4*>(x + row0 * D_);
    float4* xs4 = reinterpret_cast<float4*>(&xs[0][0]);
    #pragma unroll
    for (int i = 0; i < 4; ++i) xs4[i * 256 + tid] = xg[i * 256 + tid];
  }

  float acc[HG_ROWS];
  {
    float b0 = bias[tid];
    #pragma unroll
    for (int r = 0; r < HG_ROWS; ++r) acc[r] = b0;
  }

  for (int c = 0; c < 4; ++c) {
    __syncthreads();
    {
      const float4* vg = reinterpret_cast<const float4*>(V + (size_t)(c * 32) * U_);
      float4* vs4 = reinterpret_cast<float4*>(&vs[0][0]);
      #pragma unroll
      for (int i = 0; i < 8; ++i) vs4[i * 256 + tid] = vg[i * 256 + tid];
    }
    __syncthreads();

    #pragma unroll 2
    for (int d4 = 0; d4 < 8; ++d4) {
      float v0 = vs[d4 * 4 + 0][tid];
      float v1 = vs[d4 * 4 + 1][tid];
      float v2 = vs[d4 * 4 + 2][tid];
      float v3 = vs[d4 * 4 + 3][tid];
      #pragma unroll
      for (int r = 0; r < HG_ROWS; ++r) {
        float4 xr = *reinterpret_cast<const float4*>(&xs[r][c * 32 + d4 * 4]);
        acc[r] = fmaf(xr.x, v0, acc[r]);
        acc[r] = fmaf(xr.y, v1, acc[r]);
        acc[r] = fmaf(xr.z, v2, acc[r]);
        acc[r] = fmaf(xr.w, v3, acc[r]);
      }
    }
  }

  float* og = out + row0 * U_;
  #pragma unroll
  for (int r = 0; r < HG_ROWS; ++r) og[(size_t)r * U_ + tid] = acc[r];
}

// ================= Kernel 2: MFMA scan ======================================
// 8 blocks x 256 threads (4 waves). Per step: Z[16][256] = S_bf16 @ M_bf16.
// M fragments permanent in VGPRs; S double-buffered in LDS (swizzled).
// KEY CHANGE vs r6: raw s_barrier + lgkmcnt(0) only (T3/T4 pattern) — global
// stores stay fire-and-forget and the 2-deep h prefetch rides ACROSS steps
// instead of being drained by __syncthreads' implicit vmcnt(0).
// Running u32 byte-offsets (saddr+voffset) replace per-step 64-bit addr math.
__global__ __launch_bounds__(256, 1) void scan_mfma_kernel(
    const float* __restrict__ W, const float* __restrict__ x0,
    float* __restrict__ out)
{
  __shared__ __align__(16) char sbuf[2][16 * 512];

  const int tid = threadIdx.x;
  const int w = tid >> 6;     // wave 0..3
  const int l = tid & 63;
  const int g = l >> 4;       // 0..3
  const int n16 = l & 15;
  const int b0 = blockIdx.x * NB;

  // ---- B fragments (static M columns); slot map (g,e) -> k = kt*32+8g+e,
  // identical to the A-side map, so any hw-internal k permutation cancels.
  bf16x8 bfrag[4][8];
  #pragma unroll
  for (int c = 0; c < 4; ++c) {
    const int u = 64 * w + 16 * c + n16;
    #pragma unroll
    for (int kt = 0; kt < 8; ++kt) {
      #pragma unroll
      for (int e = 0; e < 8; ++e) {
        const int k = kt * 32 + 8 * g + e;
        float mv = W[(size_t)k * U_ + u] - W[(size_t)u * U_ + k]
                   - ((k == u) ? GAMMA_ : 0.0f);
        bfrag[c][kt][e] = f2bf(mv);
      }
    }
  }

  // ---- f32 master state; C/D layout (m89-verified): col=l&15, row=4g+reg
  float s_f32[4][4];
  #pragma unroll
  for (int c = 0; c < 4; ++c) {
    float v = x0[64 * w + 16 * c + n16];
    #pragma unroll
    for (int i = 0; i < 4; ++i) s_f32[c][i] = v;
  }

  // ---- init bf16 state buffer 0
  {
    short v = f2bf(x0[tid]);
    #pragma unroll
    for (int j = 0; j < 16; ++j)
      *(short*)(&sbuf[0][sb_byte(j, tid)]) = v;
  }

  // ---- running byte offsets into out[] for the 16 (c,i) slots.
  // soff tracks element (b0+4g+i, t, u); loff tracks the h-load target
  // (t+2 clamped to T-1). Max offset 128 MB fits u32.
  unsigned soff[4][4], loff[4][4];
  #pragma unroll
  for (int c = 0; c < 4; ++c) {
    const int u = 64 * w + 16 * c + n16;
    #pragma unroll
    for (int i = 0; i < 4; ++i) {
      unsigned base = (unsigned)(((b0 + 4 * g + i) * T_) * U_ + u) * 4u;
      soff[c][i] = base;
      loff[c][i] = base;          // load issued at +2048 imm (= t+2 rows)
    }
  }

  __syncthreads();  // one-time full barrier after LDS init (drain is fine here)

  const char* outc = (const char*)out;
  // ---- preload h[0], h[1]
  float h0[4][4], h1[4][4];
  #pragma unroll
  for (int c = 0; c < 4; ++c)
    #pragma unroll
    for (int i = 0; i < 4; ++i) {
      h0[c][i] = *(const float*)(outc + soff[c][i]);
      h1[c][i] = *(const float*)(outc + soff[c][i] + 1024);
    }

  for (int t = 0; t < T_; ++t) {
    // ---- issue h[t+2] loads first (fire-and-forget; complete ~2 steps later)
    float h2[4][4];
    #pragma unroll
    for (int c = 0; c < 4; ++c)
      #pragma unroll
      for (int i = 0; i < 4; ++i)
        h2[c][i] = *(const float*)(outc + loff[c][i] + 2048);

    // ---- A fragments from sbuf[t&1] (row n16, slots (g,e) -> u=kt*32+8g+e)
    const char* sb = sbuf[t & 1];
    bf16x8 af[8];
    #pragma unroll
    for (int kt = 0; kt < 8; ++kt)
      af[kt] = *(const bf16x8*)(sb + n16 * 512
                                + ((kt * 64 + 16 * g) ^ ((n16 & 7) << 4)));

    // ---- MFMA: kt-outer, c-inner (4 independent chains -> ILP-4)
    f32x4 acc[4];
    #pragma unroll
    for (int c = 0; c < 4; ++c) acc[c] = (f32x4){0.f, 0.f, 0.f, 0.f};
    #pragma unroll
    for (int kt = 0; kt < 8; ++kt)
      #pragma unroll
      for (int c = 0; c < 4; ++c)
        acc[c] = __builtin_amdgcn_mfma_f32_16x16x32_bf16(
            af[kt], bfrag[c][kt], acc[c], 0, 0, 0);

    // ---- epilogue
    char* sw = sbuf[(t & 1) ^ 1];
    float* outw = (float*)out;
    #pragma unroll
    for (int c = 0; c < 4; ++c) {
      const int u = 64 * w + 16 * c + n16;
      #pragma unroll
      for (int i = 0; i < 4; ++i) {
        float z = acc[c][i] + h0[c][i];
        float e2 = __expf(2.0f * z);
        float th = 1.0f - 2.0f * __builtin_amdgcn_rcpf(e2 + 1.0f);
        float ns = s_f32[c][i] + EPS_ * th;
        s_f32[c][i] = ns;
        *(short*)(sw + sb_byte(4 * g + i, u)) = f2bf(ns);
        *(float*)((char*)outw + soff[c][i]) = ns;   // fire-and-forget
      }
    }

    // ---- rotate prefetch regs, advance offsets (uniform adv -> SALU select)
    const unsigned adv = (t < T_ - 3) ? 1024u : 0u;
    #pragma unroll
    for (int c = 0; c < 4; ++c)
      #pragma unroll
      for (int i = 0; i < 4; ++i) {
        h0[c][i] = h1[c][i];
        h1[c][i] = h2[c][i];
        soff[c][i] += 1024u;
        loff[c][i] += adv;
      }

    // ---- raw barrier: LDS drained, global ops stay in flight (T3/T4)
    asm volatile("s_waitcnt lgkmcnt(0)" ::: "memory");
    __builtin_amdgcn_s_barrier();
    asm volatile("" ::: "memory");
    __builtin_amdgcn_sched_barrier(0);
  }
}

extern "C" void kernel_launch(void* const* d_in, const int* in_sizes, int n_in,
                              void* d_out, int out_size, void* d_ws, size_t ws_size,
                              hipStream_t stream) {
  const float* x    = (const float*)d_in[0];  // [B,T,D]
  const float* V    = (const float*)d_in[1];  // [D,U]
  const float* W    = (const float*)d_in[2];  // [U,U]
  const float* bias = (const float*)d_in[3];  // [U]
  const float* x0   = (const float*)d_in[4];  // [U]
  float* out = (float*)d_out;                 // [B,T,U]

  // Stage h = x@V + bias into d_out, then scan overwrites it in place.
  h_gemm_kernel<<<(B_ * T_) / HG_ROWS, 256, 0, stream>>>(x, V, bias, out);
  scan_mfma_kernel<<<NBLK, 256, 0, stream>>>(W, x0, out);
}

// Round 8
// 1042.993 us; speedup vs baseline: 1.4648x; 1.4648x over previous
//
#include <hip/hip_runtime.h>
#include <cmath>

#define B_ 128
#define T_ 1024
#define D_ 128
#define U_ 256
#define EPS_ 0.01f
#define GAMMA_ 0.01f
#define NB 16            // batches per scan block
#define NBLK (B_ / NB)   // 8 scan blocks

typedef __attribute__((ext_vector_type(8))) short bf16x8;
typedef __attribute__((ext_vector_type(4))) float f32x4;

// f32 -> bf16 round-to-nearest-even
static __device__ __forceinline__ short f2bf(float f) {
  unsigned u = __builtin_bit_cast(unsigned, f);
  unsigned r = (u + 0x7FFFu + ((u >> 16) & 1u)) >> 16;
  return (short)r;
}

// Swizzled byte offset into one bf16 state buffer s[16 rows][256 units].
// Row stride 512 B; XOR bits 4-6 with (row&7) -> b128 fragment reads
// conflict-free; b16 writes land 2-way (free).
static __device__ __forceinline__ int sb_byte(int j, int u) {
  return j * 512 + ((u * 2) ^ ((j & 7) << 4));
}

// ================= Kernel 1: h = x @ V + bias (f32, unchanged) =============
#define HG_ROWS 32

__global__ __launch_bounds__(256) void h_gemm_kernel(
    const float* __restrict__ x, const float* __restrict__ V,
    const float* __restrict__ bias, float* __restrict__ out)
{
  const int tid = threadIdx.x;
  const size_t row0 = (size_t)blockIdx.x * HG_ROWS;

  __shared__ float xs[HG_ROWS][D_];
  __shared__ float vs[32][U_];

  {
    const float4* xg = reinterpret_cast<const float4*>(x + row0 * D_);
    float4* xs4 = reinterpret_cast<float4*>(&xs[0][0]);
    #pragma unroll
    for (int i = 0; i < 4; ++i) xs4[i * 256 + tid] = xg[i * 256 + tid];
  }

  float acc[HG_ROWS];
  {
    float b0 = bias[tid];
    #pragma unroll
    for (int r = 0; r < HG_ROWS; ++r) acc[r] = b0;
  }

  for (int c = 0; c < 4; ++c) {
    __syncthreads();
    {
      const float4* vg = reinterpret_cast<const float4*>(V + (size_t)(c * 32) * U_);
      float4* vs4 = reinterpret_cast<float4*>(&vs[0][0]);
      #pragma unroll
      for (int i = 0; i < 8; ++i) vs4[i * 256 + tid] = vg[i * 256 + tid];
    }
    __syncthreads();

    #pragma unroll 2
    for (int d4 = 0; d4 < 8; ++d4) {
      float v0 = vs[d4 * 4 + 0][tid];
      float v1 = vs[d4 * 4 + 1][tid];
      float v2 = vs[d4 * 4 + 2][tid];
      float v3 = vs[d4 * 4 + 3][tid];
      #pragma unroll
      for (int r = 0; r < HG_ROWS; ++r) {
        float4 xr = *reinterpret_cast<const float4*>(&xs[r][c * 32 + d4 * 4]);
        acc[r] = fmaf(xr.x, v0, acc[r]);
        acc[r] = fmaf(xr.y, v1, acc[r]);
        acc[r] = fmaf(xr.z, v2, acc[r]);
        acc[r] = fmaf(xr.w, v3, acc[r]);
      }
    }
  }

  float* og = out + row0 * U_;
  #pragma unroll
  for (int r = 0; r < HG_ROWS; ++r) og[(size_t)r * U_ + tid] = acc[r];
}

// ================= Kernel 2: MFMA scan, 8 waves =============================
// 8 blocks x 512 threads (8 waves, 2/SIMD -> TLP). Per step:
//   Z[16][256] = S_bf16 @ M_bf16 via mfma_f32_16x16x32_bf16.
// Wave w owns u-tiles {2w, 2w+1} (32 cols). M fragments permanent in VGPRs
// (2x8 bf16x8 = 64 VGPR). S double-buffered in LDS (swizzled). Plain
// __syncthreads per step (r7's raw-barrier experiment regressed). 1-deep h
// prefetch: issue h[t+1] at top of step t (~full step of latency cover).
// Slot map (g,e) -> k = kt*32+8g+e identical on A and B sides (permutation
// cancels); C/D layout (m89-verified): col = l&15, row = 4*(l>>4) + reg.
__global__ __launch_bounds__(512, 2) void scan_mfma_kernel(
    const float* __restrict__ W, const float* __restrict__ x0,
    float* __restrict__ out)
{
  __shared__ __align__(16) char sbuf[2][16 * 512];

  const int tid = threadIdx.x;
  const int w = tid >> 6;     // wave 0..7
  const int l = tid & 63;
  const int g = l >> 4;       // 0..3
  const int n16 = l & 15;
  const int b0 = blockIdx.x * NB;

  // ---- B fragments (static M columns), 2 c-tiles per wave
  bf16x8 bfrag[2][8];
  #pragma unroll
  for (int c = 0; c < 2; ++c) {
    const int u = 32 * w + 16 * c + n16;
    #pragma unroll
    for (int kt = 0; kt < 8; ++kt) {
      #pragma unroll
      for (int e = 0; e < 8; ++e) {
        const int k = kt * 32 + 8 * g + e;
        float mv = W[(size_t)k * U_ + u] - W[(size_t)u * U_ + k]
                   - ((k == u) ? GAMMA_ : 0.0f);
        bfrag[c][kt][e] = f2bf(mv);
      }
    }
  }

  // ---- f32 master state: lane owns rows 4g+i, cols u(c)
  float s_f32[2][4];
  #pragma unroll
  for (int c = 0; c < 2; ++c) {
    float v = x0[32 * w + 16 * c + n16];
    #pragma unroll
    for (int i = 0; i < 4; ++i) s_f32[c][i] = v;
  }

  // ---- init bf16 state buffer 0 (threads 0..255 handle unit u=tid)
  if (tid < U_) {
    short v = f2bf(x0[tid]);
    #pragma unroll
    for (int j = 0; j < 16; ++j)
      *(short*)(&sbuf[0][sb_byte(j, tid)]) = v;
  }
  __syncthreads();

  // ---- h preload for t=0
  float h_cur[2][4], h_nxt[2][4];
  #pragma unroll
  for (int c = 0; c < 2; ++c) {
    const int u = 32 * w + 16 * c + n16;
    #pragma unroll
    for (int i = 0; i < 4; ++i)
      h_cur[c][i] = out[(size_t)(b0 + 4 * g + i) * (T_ * U_) + u];
  }

  for (int t = 0; t < T_; ++t) {
    // ---- issue h[t+1] loads first (latency hidden under MFMA + epilogue)
    {
      const int tn = (t + 1 < T_) ? t + 1 : t;
      #pragma unroll
      for (int c = 0; c < 2; ++c) {
        const int u = 32 * w + 16 * c + n16;
        #pragma unroll
        for (int i = 0; i < 4; ++i)
          h_nxt[c][i] = out[(size_t)(b0 + 4 * g + i) * (T_ * U_)
                            + (size_t)tn * U_ + u];
      }
    }

    // ---- A fragments from sbuf[t&1]: row n16, slot (g,e) -> u = kt*32+8g+e
    const char* sb = sbuf[t & 1];
    bf16x8 af[8];
    #pragma unroll
    for (int kt = 0; kt < 8; ++kt)
      af[kt] = *(const bf16x8*)(sb + n16 * 512
                                + ((kt * 64 + 16 * g) ^ ((n16 & 7) << 4)));

    // ---- MFMA: 2 independent acc chains x 8 k-tiles
    f32x4 acc[2];
    #pragma unroll
    for (int c = 0; c < 2; ++c) acc[c] = (f32x4){0.f, 0.f, 0.f, 0.f};
    #pragma unroll
    for (int kt = 0; kt < 8; ++kt)
      #pragma unroll
      for (int c = 0; c < 2; ++c)
        acc[c] = __builtin_amdgcn_mfma_f32_16x16x32_bf16(
            af[kt], bfrag[c][kt], acc[c], 0, 0, 0);

    // ---- epilogue: z = d + h; tanh; state update; bf16 S write + f32 out
    char* sw = sbuf[(t & 1) ^ 1];
    #pragma unroll
    for (int c = 0; c < 2; ++c) {
      const int u = 32 * w + 16 * c + n16;
      #pragma unroll
      for (int i = 0; i < 4; ++i) {
        float z = acc[c][i] + h_cur[c][i];
        float e2 = __expf(2.0f * z);
        float th = 1.0f - 2.0f * __builtin_amdgcn_rcpf(e2 + 1.0f);
        float ns = s_f32[c][i] + EPS_ * th;
        s_f32[c][i] = ns;
        *(short*)(sw + sb_byte(4 * g + i, u)) = f2bf(ns);
        out[(size_t)(b0 + 4 * g + i) * (T_ * U_) + (size_t)t * U_ + u] = ns;
      }
    }

    // ---- rotate h prefetch
    #pragma unroll
    for (int c = 0; c < 2; ++c)
      #pragma unroll
      for (int i = 0; i < 4; ++i) h_cur[c][i] = h_nxt[c][i];

    __syncthreads();
  }
}

extern "C" void kernel_launch(void* const* d_in, const int* in_sizes, int n_in,
                              void* d_out, int out_size, void* d_ws, size_t ws_size,
                              hipStream_t stream) {
  const float* x    = (const float*)d_in[0];  // [B,T,D]
  const float* V    = (const float*)d_in[1];  // [D,U]
  const float* W    = (const float*)d_in[2];  // [U,U]
  const float* bias = (const float*)d_in[3];  // [U]
  const float* x0   = (const float*)d_in[4];  // [U]
  float* out = (float*)d_out;                 // [B,T,U]

  // Stage h = x@V + bias into d_out, then scan overwrites it in place.
  h_gemm_kernel<<<(B_ * T_) / HG_ROWS, 256, 0, stream>>>(x, V, bias, out);
  scan_mfma_kernel<<<NBLK, 512, 0, stream>>>(W, x0, out);
}